// Round 10
// baseline (87.327 us; speedup 1.0000x reference)
//
#include <hip/hip_runtime.h>
#include <limits.h>

// Problem constants (fixed by reference setup_inputs)
#define W_IMG 320
#define H_IMG 240
#define N_VIEW 2            // B*V = 1*2
#define DX_ 192
#define DY_ 192
#define DZ_ 96
#define NVOX 80000
#define CFEAT 128
#define NSTEPS 156
#define NPIX (N_VIEW * H_IMG * W_IMG)   // 153600

#define NCELLS (DZ_ * DY_ * DX_)        // 3,538,944
#define WPR (DX_ / 32)                  // 6 words per x-row
#define NWORDS (NCELLS / 32)            // 110,592

// d_out float offsets (concatenated return order)
#define OFF_PROJ 0
#define OFF_IDX  (NPIX * CFEAT)            // 19,660,800
#define OFF_W    (OFF_IDX + NPIX * 8)      // 20,889,600
#define OFF_MAP  (OFF_W + NPIX * 8)        // 22,118,400

#define GATHER_BLOCKS (NPIX * 32 / 256)    // 19200

// ------- Kernel B: dilate, 4 threads/word (one per dz,dy row) -----------
// dilated bit(x,y,z) = OR of (occ != -1) over (x..x+1, y..y+1, z..z+1),
// upper-clipped — identical to the reference's 8-corner validity OR.
__global__ __launch_bounds__(256) void dilate_v2_kernel(
    const int* __restrict__ occ, unsigned* __restrict__ dil,
    float* __restrict__ out_map)
{
    int g = blockIdx.x * 256 + threadIdx.x;     // NWORDS*4 threads exactly
    // fold in: zero the 80000-float histogram (first 20000 threads, float4)
    if (g < NVOX / 4) ((float4*)out_map)[g] = make_float4(0.f, 0.f, 0.f, 0.f);

    int w = g >> 2;                              // output word
    int q = g & 3;                               // row selector: dz=q>>1, dy=q&1
    int wx = w % WPR;
    int y  = (w / WPR) % DY_;
    int z  = w / (WPR * DY_);
    int zz = z + (q >> 1);
    int yy = y + (q & 1);

    unsigned acc = 0;
    if (zz < DZ_ && yy < DY_) {
        const int* row = occ + (zz * DY_ + yy) * DX_ + (wx << 5);
        const int4* r4 = (const int4*)row;       // 128B-aligned
        unsigned m = 0;
        #pragma unroll
        for (int k = 0; k < 8; ++k) {            // 8 independent int4 loads
            int4 qd = r4[k];
            unsigned b = (unsigned)(qd.x != -1)
                       | ((unsigned)(qd.y != -1) << 1)
                       | ((unsigned)(qd.z != -1) << 2)
                       | ((unsigned)(qd.w != -1) << 3);
            m |= b << (k * 4);
        }
        unsigned nxt = (wx + 1 < WPR) ? (unsigned)(row[32] != -1) : 0u;
        acc = m | (m >> 1) | (nxt << 31);
    }
    // OR across the 4-lane quad (lanes 4k..4k+3)
    acc |= __shfl_xor(acc, 1);
    acc |= __shfl_xor(acc, 2);
    if (q == 0) dil[w] = acc;
}

// -------- Kernel C: raycast (4 lanes/pixel) + direct-atomic histogram ---
__device__ __forceinline__ bool slow_any(const int* __restrict__ occ,
                                         int ix, int iy, int iz)
{
    bool any = false;
    #pragma unroll
    for (int c = 0; c < 8; ++c) {
        int ddz = c >> 2, ddy = (c >> 1) & 1, ddx = c & 1;
        int cxl = ix + ddx, cyl = iy + ddy, czl = iz + ddz;
        bool inb = ((unsigned)cxl < DX_) & ((unsigned)cyl < DY_) & ((unsigned)czl < DZ_);
        int xc = min(max(cxl, 0), DX_ - 1);
        int yc = min(max(cyl, 0), DY_ - 1);
        int zc = min(max(czl, 0), DZ_ - 1);
        int idx = occ[(zc * DY_ + yc) * DX_ + xc];
        any = any | (inb & (idx != -1));
    }
    return any;
}

__global__ __launch_bounds__(256) void raycast_kernel(
    const float* __restrict__ vm,     // (1,V,4,4)
    const float* __restrict__ intr,   // (1,V,4)
    const int*   __restrict__ occ,    // (DZ,DY,DX)
    const unsigned* __restrict__ dil, // dilated bitmask
    float* __restrict__ out_idx,      // NPIX*8 (float-encoded ints)
    float* __restrict__ out_w,        // NPIX*8
    float* __restrict__ out_map)      // NVOX (zeroed by dilate)
{
    int t    = blockIdx.x * 256 + threadIdx.x;
    int pix  = t >> 2;                 // 4 lanes per pixel
    int sub  = t & 3;
    int lane = threadIdx.x & 63;

    int v   = pix / (H_IMG * W_IMG);
    int rem = pix - v * (H_IMG * W_IMG);
    int h   = rem / W_IMG;
    int w   = rem - h * W_IMG;

    const float* M = vm + v * 16;
    const float* I = intr + v * 4;
    float fx = I[0], fy = I[1], cx = I[2], cy = I[3];
    float uu = (float)w + 0.5f;
    float vv = (float)h + 0.5f;
    // dirs_cam, each op individually rounded (match numpy fp32, no FMA)
    float dc0 = __fdiv_rn(__fsub_rn(uu, cx), fx);
    float dc1 = __fdiv_rn(__fsub_rn(vv, cy), fy);
    float dc2 = 1.0f;
    float dir0 = __fadd_rn(__fadd_rn(__fmul_rn(M[0], dc0), __fmul_rn(M[1], dc1)), __fmul_rn(M[2], dc2));
    float dir1 = __fadd_rn(__fadd_rn(__fmul_rn(M[4], dc0), __fmul_rn(M[5], dc1)), __fmul_rn(M[6], dc2));
    float dir2 = __fadd_rn(__fadd_rn(__fmul_rn(M[8], dc0), __fmul_rn(M[9], dc1)), __fmul_rn(M[10], dc2));
    float t0 = M[3], t1 = M[7], t2 = M[11];

    // -------- march: 32-step window/round, 8 independent loads/lane ----
    int s_hit = INT_MAX;
    for (int base = 0; base < NSTEPS; base += 32) {
        int smin = INT_MAX;
        int need = 0;                          // deferred slow-path mask
        #pragma unroll
        for (int j = 0; j < 8; ++j) {
            int s = base + sub + 4 * j;
            float d  = __fadd_rn(2.0f, __fmul_rn(0.5f, (float)s)); // exact
            float px = __fsub_rn(__fadd_rn(t0, __fmul_rn(d, dir0)), 0.5f);
            float py = __fsub_rn(__fadd_rn(t1, __fmul_rn(d, dir1)), 0.5f);
            float pz = __fsub_rn(__fadd_rn(t2, __fmul_rn(d, dir2)), 0.5f);
            int ix = (int)floorf(px);
            int iy = (int)floorf(py);
            int iz = (int)floorf(pz);
            bool inb3 = ((unsigned)ix < DX_) & ((unsigned)iy < DY_) & ((unsigned)iz < DZ_);
            int addr = inb3 ? ((iz * DY_ + iy) * WPR + (ix >> 5)) : 0;
            unsigned wd = dil[addr];           // 8 independent loads in flight
            bool ok = (s < NSTEPS);
            bool any = ok & inb3 & (bool)((wd >> (ix & 31)) & 1u);
            bool ns  = ok & !inb3 & (ix >= -1) & (ix < DX_) & (iy >= -1) & (iy < DY_)
                          & (iz >= -1) & (iz < DZ_);
            need |= (ns ? 1 : 0) << j;
            if (any) smin = min(smin, s);
        }
        if (__builtin_expect(need, 0)) {       // cold: boundary cells only
            for (int j = 0; j < 8; ++j) {
                if ((need >> j) & 1) {
                    int s = base + sub + 4 * j;
                    float d  = __fadd_rn(2.0f, __fmul_rn(0.5f, (float)s));
                    float px = __fsub_rn(__fadd_rn(t0, __fmul_rn(d, dir0)), 0.5f);
                    float py = __fsub_rn(__fadd_rn(t1, __fmul_rn(d, dir1)), 0.5f);
                    float pz = __fsub_rn(__fadd_rn(t2, __fmul_rn(d, dir2)), 0.5f);
                    int ix = (int)floorf(px);
                    int iy = (int)floorf(py);
                    int iz = (int)floorf(pz);
                    if (slow_any(occ, ix, iy, iz)) smin = min(smin, s);
                }
            }
        }
        // min over the 4-lane group (xor 1,2 stay within the group)
        smin = min(smin, __shfl_xor(smin, 1));
        smin = min(smin, __shfl_xor(smin, 2));
        if (smin != INT_MAX) { s_hit = smin; break; }
    }

    int hit = 0;
    int bx = 0, by = 0, bz = 0;
    float fr0 = 0.f, fr1 = 0.f, fr2 = 0.f;
    if (s_hit != INT_MAX) {
        hit = 1;
        float d  = __fadd_rn(2.0f, __fmul_rn(0.5f, (float)s_hit));
        float px = __fsub_rn(__fadd_rn(t0, __fmul_rn(d, dir0)), 0.5f);
        float py = __fsub_rn(__fadd_rn(t1, __fmul_rn(d, dir1)), 0.5f);
        float pz = __fsub_rn(__fadd_rn(t2, __fmul_rn(d, dir2)), 0.5f);
        float fpx = floorf(px), fpy = floorf(py), fpz = floorf(pz);
        bx = (int)fpx; by = (int)fpy; bz = (int)fpz;
        fr0 = px - fpx; fr1 = py - fpy; fr2 = pz - fpz; // exact (Sterbenz)
    }

    // -------- finalize (all 4 lanes compute identically; loads broadcast)
    float ws8[8];
    int   id8[8];
    float wsum = 0.0f;
    #pragma unroll
    for (int c = 0; c < 8; ++c) {
        float wk = 0.0f;
        int idv = -1;
        if (hit) {
            int ddz = c >> 2, ddy = (c >> 1) & 1, ddx = c & 1;
            int cxl = bx + ddx, cyl = by + ddy, czl = bz + ddz;
            bool inb = ((unsigned)cxl < DX_) & ((unsigned)cyl < DY_) & ((unsigned)czl < DZ_);
            int xc = min(max(cxl, 0), DX_ - 1);
            int yc = min(max(cyl, 0), DY_ - 1);
            int zc = min(max(czl, 0), DZ_ - 1);
            int idx = occ[(zc * DY_ + yc) * DX_ + xc];
            bool valid = inb & (idx != -1);
            float gw = ddz ? fr2 : (1.0f - fr2);
            gw = __fmul_rn(gw, ddy ? fr1 : (1.0f - fr1));
            gw = __fmul_rn(gw, ddx ? fr0 : (1.0f - fr0));
            if (valid) { wk = gw; idv = idx; }
        }
        ws8[c] = wk;
        id8[c] = idv;
        wsum = __fadd_rn(wsum, wk);   // sequential order k=0..7
    }
    float inv = __fdiv_rn(1.0f, __fadd_rn(wsum, 1e-8f));

    float wn[8];
    #pragma unroll
    for (int c = 0; c < 8; ++c) wn[c] = __fmul_rn(ws8[c], inv);

    // one float4 store per lane (all 4 lanes active)
    float4* w4 = (float4*)out_w;
    float4* i4 = (float4*)out_idx;
    if (sub == 0)      w4[pix * 2]     = make_float4(wn[0], wn[1], wn[2], wn[3]);
    else if (sub == 1) w4[pix * 2 + 1] = make_float4(wn[4], wn[5], wn[6], wn[7]);
    else if (sub == 2) i4[pix * 2]     = make_float4((float)id8[0], (float)id8[1], (float)id8[2], (float)id8[3]);
    else               i4[pix * 2 + 1] = make_float4((float)id8[4], (float)id8[5], (float)id8[6], (float)id8[7]);

    // -------- fused histogram: run-length aggregation, direct atomics ---
    #pragma unroll
    for (int c = 0; c < 8; ++c) {
        int vid  = id8[c];
        int prev = __shfl(vid, max(lane - 4, 0));   // previous pixel's vid
        bool leader = (lane < 4) || (vid != prev);  // uniform within 4-lane group
        unsigned long long lm = __ballot(leader);
        int gl = lane & ~3;                          // group base lane
        unsigned long long higher = (gl == 60) ? 0ULL : (lm >> (gl + 4));
        int cnt = higher ? (((__ffsll(higher) - 1) >> 2) + 1) : ((64 - gl) >> 2);
        if (sub == 0 && leader && vid >= 0) atomicAdd(&out_map[vid], (float)cnt);
    }
}

// ---------------- Kernel D: feature gather (32 lanes/pixel) -------------
__global__ __launch_bounds__(256) void gather_kernel(
    const float* __restrict__ feat,     // NVOX*CFEAT
    const float* __restrict__ out_idx,  // NPIX*8
    const float* __restrict__ out_w,    // NPIX*8
    float* __restrict__ proj)           // NPIX*CFEAT
{
    int t = blockIdx.x * 256 + threadIdx.x;
    int pix  = t >> 5;       // 32 lanes per pixel
    int lane = t & 31;       // each lane: 4 channels via float4

    const float4* f4 = (const float4*)feat;
    float4 acc = make_float4(0.f, 0.f, 0.f, 0.f);
    #pragma unroll
    for (int c = 0; c < 8; ++c) {
        float wk = out_w[pix * 8 + c];
        if (wk != 0.0f) {
            int idx = (int)out_idx[pix * 8 + c];   // >=0 whenever wk!=0
            float4 f = f4[idx * (CFEAT / 4) + lane];
            acc.x += wk * f.x;
            acc.y += wk * f.y;
            acc.z += wk * f.z;
            acc.w += wk * f.w;
        }
    }
    ((float4*)proj)[pix * (CFEAT / 4) + lane] = acc;
}

extern "C" void kernel_launch(void* const* d_in, const int* in_sizes, int n_in,
                              void* d_out, int out_size, void* d_ws, size_t ws_size,
                              hipStream_t stream) {
    const float* feat = (const float*)d_in[0];
    const float* vm   = (const float*)d_in[1];
    const float* intr = (const float*)d_in[2];
    const int*   occ  = (const int*)d_in[3];
    float* out = (float*)d_out;

    float* out_proj = out + OFF_PROJ;
    float* out_idx  = out + OFF_IDX;
    float* out_w    = out + OFF_W;
    float* out_map  = out + OFF_MAP;

    unsigned* dil = (unsigned*)d_ws;            // 442,368 B

    // dilate (4 threads/word) also zeroes out_map; stream order guarantees
    // it precedes raycast's fused direct atomics.
    dilate_v2_kernel<<<(NWORDS * 4) / 256, 256, 0, stream>>>(occ, dil, out_map);

    raycast_kernel<<<(NPIX * 4) / 256, 256, 0, stream>>>(
        vm, intr, occ, dil, out_idx, out_w, out_map);

    gather_kernel<<<GATHER_BLOCKS, 256, 0, stream>>>(
        feat, out_idx, out_w, out_proj);
}

// Round 11
// 54.729 us; speedup vs baseline: 1.5956x; 1.5956x over previous
//
#include <hip/hip_runtime.h>
#include <limits.h>

// Problem constants (fixed by reference setup_inputs)
#define W_IMG 320
#define H_IMG 240
#define N_VIEW 2            // B*V = 1*2
#define DX_ 192
#define DY_ 192
#define DZ_ 96
#define NVOX 80000
#define CFEAT 128
#define NSTEPS 156
#define NPIX (N_VIEW * H_IMG * W_IMG)   // 153600

#define NCELLS (DZ_ * DY_ * DX_)        // 3,538,944
#define WPR (DX_ / 32)                  // 6 words per x-row
#define NWORDS (NCELLS / 32)            // 110,592

// d_out float offsets (concatenated return order)
#define OFF_PROJ 0
#define OFF_IDX  (NPIX * CFEAT)            // 19,660,800
#define OFF_W    (OFF_IDX + NPIX * 8)      // 20,889,600
#define OFF_MAP  (OFF_W + NPIX * 8)        // 22,118,400

// d_ws layout (bytes): dil [0, 442368) | histogram copies after
#define WS_COPIES_OFF 442368

#define GATHER_BLOCKS (NPIX * 32 / 256)    // 19200

typedef float f4v __attribute__((ext_vector_type(4)));

// ------- Kernel B: dilate, 4 threads/word + zero histogram copies -------
// dilated bit(x,y,z) = OR of (occ != -1) over (x..x+1, y..y+1, z..z+1),
// upper-clipped — identical to the reference's 8-corner validity OR.
__global__ __launch_bounds__(256) void dilate_v2_kernel(
    const int* __restrict__ occ, unsigned* __restrict__ dil,
    float* __restrict__ zero_tgt, int zero_n4)
{
    int g = blockIdx.x * 256 + threadIdx.x;     // NWORDS*4 threads exactly
    // fold in: zero the histogram copies (442K threads cover <=160K float4)
    if (g < zero_n4) ((float4*)zero_tgt)[g] = make_float4(0.f, 0.f, 0.f, 0.f);

    int w = g >> 2;                              // output word
    int q = g & 3;                               // row selector: dz=q>>1, dy=q&1
    int wx = w % WPR;
    int y  = (w / WPR) % DY_;
    int z  = w / (WPR * DY_);
    int zz = z + (q >> 1);
    int yy = y + (q & 1);

    unsigned acc = 0;
    if (zz < DZ_ && yy < DY_) {
        const int* row = occ + (zz * DY_ + yy) * DX_ + (wx << 5);
        const int4* r4 = (const int4*)row;       // 128B-aligned
        unsigned m = 0;
        #pragma unroll
        for (int k = 0; k < 8; ++k) {            // 8 independent int4 loads
            int4 qd = r4[k];
            unsigned b = (unsigned)(qd.x != -1)
                       | ((unsigned)(qd.y != -1) << 1)
                       | ((unsigned)(qd.z != -1) << 2)
                       | ((unsigned)(qd.w != -1) << 3);
            m |= b << (k * 4);
        }
        unsigned nxt = (wx + 1 < WPR) ? (unsigned)(row[32] != -1) : 0u;
        acc = m | (m >> 1) | (nxt << 31);
    }
    // OR across the 4-lane quad (lanes 4k..4k+3)
    acc |= __shfl_xor(acc, 1);
    acc |= __shfl_xor(acc, 2);
    if (q == 0) dil[w] = acc;
}

// -------- Kernel C: raycast (4 lanes/pixel) + privatized histogram ------
__device__ __forceinline__ bool slow_any(const int* __restrict__ occ,
                                         int ix, int iy, int iz)
{
    bool any = false;
    #pragma unroll
    for (int c = 0; c < 8; ++c) {
        int ddz = c >> 2, ddy = (c >> 1) & 1, ddx = c & 1;
        int cxl = ix + ddx, cyl = iy + ddy, czl = iz + ddz;
        bool inb = ((unsigned)cxl < DX_) & ((unsigned)cyl < DY_) & ((unsigned)czl < DZ_);
        int xc = min(max(cxl, 0), DX_ - 1);
        int yc = min(max(cyl, 0), DY_ - 1);
        int zc = min(max(czl, 0), DZ_ - 1);
        int idx = occ[(zc * DY_ + yc) * DX_ + xc];
        any = any | (inb & (idx != -1));
    }
    return any;
}

__global__ __launch_bounds__(256) void raycast_kernel(
    const float* __restrict__ vm,     // (1,V,4,4)
    const float* __restrict__ intr,   // (1,V,4)
    const int*   __restrict__ occ,    // (DZ,DY,DX)
    const unsigned* __restrict__ dil, // dilated bitmask
    float* __restrict__ out_idx,      // NPIX*8 (float-encoded ints)
    float* __restrict__ out_w,        // NPIX*8
    float* __restrict__ map_base,     // histogram copies (or out_map direct)
    int copy_mask)                    // ncopies-1 (pow2-1), 0 = single target
{
    int t    = blockIdx.x * 256 + threadIdx.x;
    int pix  = t >> 2;                 // 4 lanes per pixel
    int sub  = t & 3;
    int lane = threadIdx.x & 63;

    int v   = pix / (H_IMG * W_IMG);
    int rem = pix - v * (H_IMG * W_IMG);
    int h   = rem / W_IMG;
    int w   = rem - h * W_IMG;

    const float* M = vm + v * 16;
    const float* I = intr + v * 4;
    float fx = I[0], fy = I[1], cx = I[2], cy = I[3];
    float uu = (float)w + 0.5f;
    float vv = (float)h + 0.5f;
    // dirs_cam, each op individually rounded (match numpy fp32, no FMA)
    float dc0 = __fdiv_rn(__fsub_rn(uu, cx), fx);
    float dc1 = __fdiv_rn(__fsub_rn(vv, cy), fy);
    float dc2 = 1.0f;
    float dir0 = __fadd_rn(__fadd_rn(__fmul_rn(M[0], dc0), __fmul_rn(M[1], dc1)), __fmul_rn(M[2], dc2));
    float dir1 = __fadd_rn(__fadd_rn(__fmul_rn(M[4], dc0), __fmul_rn(M[5], dc1)), __fmul_rn(M[6], dc2));
    float dir2 = __fadd_rn(__fadd_rn(__fmul_rn(M[8], dc0), __fmul_rn(M[9], dc1)), __fmul_rn(M[10], dc2));
    float t0 = M[3], t1 = M[7], t2 = M[11];

    // -------- march: 32-step window/round, 8 independent loads/lane ----
    int s_hit = INT_MAX;
    for (int base = 0; base < NSTEPS; base += 32) {
        int smin = INT_MAX;
        int need = 0;                          // deferred slow-path mask
        #pragma unroll
        for (int j = 0; j < 8; ++j) {
            int s = base + sub + 4 * j;
            float d  = __fadd_rn(2.0f, __fmul_rn(0.5f, (float)s)); // exact
            float px = __fsub_rn(__fadd_rn(t0, __fmul_rn(d, dir0)), 0.5f);
            float py = __fsub_rn(__fadd_rn(t1, __fmul_rn(d, dir1)), 0.5f);
            float pz = __fsub_rn(__fadd_rn(t2, __fmul_rn(d, dir2)), 0.5f);
            int ix = (int)floorf(px);
            int iy = (int)floorf(py);
            int iz = (int)floorf(pz);
            bool inb3 = ((unsigned)ix < DX_) & ((unsigned)iy < DY_) & ((unsigned)iz < DZ_);
            int addr = inb3 ? ((iz * DY_ + iy) * WPR + (ix >> 5)) : 0;
            unsigned wd = dil[addr];           // 8 independent loads in flight
            bool ok = (s < NSTEPS);
            bool any = ok & inb3 & (bool)((wd >> (ix & 31)) & 1u);
            bool ns  = ok & !inb3 & (ix >= -1) & (ix < DX_) & (iy >= -1) & (iy < DY_)
                          & (iz >= -1) & (iz < DZ_);
            need |= (ns ? 1 : 0) << j;
            if (any) smin = min(smin, s);
        }
        if (__builtin_expect(need, 0)) {       // cold: boundary cells only
            for (int j = 0; j < 8; ++j) {
                if ((need >> j) & 1) {
                    int s = base + sub + 4 * j;
                    float d  = __fadd_rn(2.0f, __fmul_rn(0.5f, (float)s));
                    float px = __fsub_rn(__fadd_rn(t0, __fmul_rn(d, dir0)), 0.5f);
                    float py = __fsub_rn(__fadd_rn(t1, __fmul_rn(d, dir1)), 0.5f);
                    float pz = __fsub_rn(__fadd_rn(t2, __fmul_rn(d, dir2)), 0.5f);
                    int ix = (int)floorf(px);
                    int iy = (int)floorf(py);
                    int iz = (int)floorf(pz);
                    if (slow_any(occ, ix, iy, iz)) smin = min(smin, s);
                }
            }
        }
        // min over the 4-lane group (xor 1,2 stay within the group)
        smin = min(smin, __shfl_xor(smin, 1));
        smin = min(smin, __shfl_xor(smin, 2));
        if (smin != INT_MAX) { s_hit = smin; break; }
    }

    int hit = 0;
    int bx = 0, by = 0, bz = 0;
    float fr0 = 0.f, fr1 = 0.f, fr2 = 0.f;
    if (s_hit != INT_MAX) {
        hit = 1;
        float d  = __fadd_rn(2.0f, __fmul_rn(0.5f, (float)s_hit));
        float px = __fsub_rn(__fadd_rn(t0, __fmul_rn(d, dir0)), 0.5f);
        float py = __fsub_rn(__fadd_rn(t1, __fmul_rn(d, dir1)), 0.5f);
        float pz = __fsub_rn(__fadd_rn(t2, __fmul_rn(d, dir2)), 0.5f);
        float fpx = floorf(px), fpy = floorf(py), fpz = floorf(pz);
        bx = (int)fpx; by = (int)fpy; bz = (int)fpz;
        fr0 = px - fpx; fr1 = py - fpy; fr2 = pz - fpz; // exact (Sterbenz)
    }

    // -------- finalize (all 4 lanes compute identically; loads broadcast)
    float ws8[8];
    int   id8[8];
    float wsum = 0.0f;
    #pragma unroll
    for (int c = 0; c < 8; ++c) {
        float wk = 0.0f;
        int idv = -1;
        if (hit) {
            int ddz = c >> 2, ddy = (c >> 1) & 1, ddx = c & 1;
            int cxl = bx + ddx, cyl = by + ddy, czl = bz + ddz;
            bool inb = ((unsigned)cxl < DX_) & ((unsigned)cyl < DY_) & ((unsigned)czl < DZ_);
            int xc = min(max(cxl, 0), DX_ - 1);
            int yc = min(max(cyl, 0), DY_ - 1);
            int zc = min(max(czl, 0), DZ_ - 1);
            int idx = occ[(zc * DY_ + yc) * DX_ + xc];
            bool valid = inb & (idx != -1);
            float gw = ddz ? fr2 : (1.0f - fr2);
            gw = __fmul_rn(gw, ddy ? fr1 : (1.0f - fr1));
            gw = __fmul_rn(gw, ddx ? fr0 : (1.0f - fr0));
            if (valid) { wk = gw; idv = idx; }
        }
        ws8[c] = wk;
        id8[c] = idv;
        wsum = __fadd_rn(wsum, wk);   // sequential order k=0..7
    }
    float inv = __fdiv_rn(1.0f, __fadd_rn(wsum, 1e-8f));

    float wn[8];
    #pragma unroll
    for (int c = 0; c < 8; ++c) wn[c] = __fmul_rn(ws8[c], inv);

    // one float4 store per lane (all 4 lanes active)
    float4* w4 = (float4*)out_w;
    float4* i4 = (float4*)out_idx;
    if (sub == 0)      w4[pix * 2]     = make_float4(wn[0], wn[1], wn[2], wn[3]);
    else if (sub == 1) w4[pix * 2 + 1] = make_float4(wn[4], wn[5], wn[6], wn[7]);
    else if (sub == 2) i4[pix * 2]     = make_float4((float)id8[0], (float)id8[1], (float)id8[2], (float)id8[3]);
    else               i4[pix * 2 + 1] = make_float4((float)id8[4], (float)id8[5], (float)id8[6], (float)id8[7]);

    // -------- fused histogram: run-length aggregation, privatized copies
    float* mymap = map_base + (int)(blockIdx.x & copy_mask) * NVOX;
    #pragma unroll
    for (int c = 0; c < 8; ++c) {
        int vid  = id8[c];
        int prev = __shfl(vid, max(lane - 4, 0));   // previous pixel's vid
        bool leader = (lane < 4) || (vid != prev);  // uniform within 4-lane group
        unsigned long long lm = __ballot(leader);
        int gl = lane & ~3;                          // group base lane
        unsigned long long higher = (gl == 60) ? 0ULL : (lm >> (gl + 4));
        int cnt = higher ? (((__ffsll(higher) - 1) >> 2) + 1) : ((64 - gl) >> 2);
        if (sub == 0 && leader && vid >= 0) atomicAdd(&mymap[vid], (float)cnt);
    }
}

// -------- Kernel D+R: feature gather + histogram reduce in tail blocks --
__global__ __launch_bounds__(256) void gather_reduce_kernel(
    const float* __restrict__ feat,     // NVOX*CFEAT
    const float* __restrict__ out_idx,  // NPIX*8
    const float* __restrict__ out_w,    // NPIX*8
    float* __restrict__ proj,           // NPIX*CFEAT
    const float* __restrict__ copies,   // histogram copies
    float* __restrict__ out_map,        // NVOX
    int nc)
{
    if (blockIdx.x >= GATHER_BLOCKS) {
        // ---- reduce phase: sum copies in fixed order (exact, integers) ----
        if (nc > 0) {
            int t = (blockIdx.x - GATHER_BLOCKS) * 256 + threadIdx.x;
            if (t < NVOX / 4) {
                const float4* c4 = (const float4*)copies;
                float4 s = c4[t];
                for (int c = 1; c < nc; ++c) {
                    float4 a = c4[c * (NVOX / 4) + t];
                    s.x += a.x; s.y += a.y; s.z += a.z; s.w += a.w;
                }
                ((float4*)out_map)[t] = s;
            }
        }
        return;
    }
    int t = blockIdx.x * 256 + threadIdx.x;
    int pix  = t >> 5;       // 32 lanes per pixel
    int lane = t & 31;       // each lane: 4 channels via float4

    const float4* f4 = (const float4*)feat;
    float4 acc = make_float4(0.f, 0.f, 0.f, 0.f);
    #pragma unroll
    for (int c = 0; c < 8; ++c) {
        float wk = out_w[pix * 8 + c];
        if (wk != 0.0f) {
            int idx = (int)out_idx[pix * 8 + c];   // >=0 whenever wk!=0
            float4 f = f4[idx * (CFEAT / 4) + lane];
            acc.x += wk * f.x;
            acc.y += wk * f.y;
            acc.z += wk * f.z;
            acc.w += wk * f.w;
        }
    }
    // nontemporal: proj is write-once, keep feat resident in L2
    f4v av = { acc.x, acc.y, acc.z, acc.w };
    __builtin_nontemporal_store(av, (f4v*)((float4*)proj + pix * (CFEAT / 4) + lane));
}

extern "C" void kernel_launch(void* const* d_in, const int* in_sizes, int n_in,
                              void* d_out, int out_size, void* d_ws, size_t ws_size,
                              hipStream_t stream) {
    const float* feat = (const float*)d_in[0];
    const float* vm   = (const float*)d_in[1];
    const float* intr = (const float*)d_in[2];
    const int*   occ  = (const int*)d_in[3];
    float* out = (float*)d_out;

    float* out_proj = out + OFF_PROJ;
    float* out_idx  = out + OFF_IDX;
    float* out_w    = out + OFF_W;
    float* out_map  = out + OFF_MAP;

    unsigned* dil = (unsigned*)d_ws;            // 442,368 B
    float* copies = (float*)((char*)d_ws + WS_COPIES_OFF);

    // pow2 histogram copies that fit in remaining workspace (deterministic)
    size_t avail = ws_size > WS_COPIES_OFF ? ws_size - WS_COPIES_OFF : 0;
    int nc = (int)(avail / (NVOX * sizeof(float)));
    nc = nc >= 8 ? 8 : (nc >= 4 ? 4 : (nc >= 2 ? 2 : (nc >= 1 ? 1 : 0)));

    float* map_base = nc ? copies : out_map;
    int copy_mask   = nc ? nc - 1 : 0;
    float* zero_tgt = nc ? copies : out_map;
    int zero_n4     = (nc ? nc : 1) * (NVOX / 4);

    dilate_v2_kernel<<<(NWORDS * 4) / 256, 256, 0, stream>>>(
        occ, dil, zero_tgt, zero_n4);

    raycast_kernel<<<(NPIX * 4) / 256, 256, 0, stream>>>(
        vm, intr, occ, dil, out_idx, out_w, map_base, copy_mask);

    int reduce_blocks = (NVOX / 4 + 255) / 256;   // 79
    gather_reduce_kernel<<<GATHER_BLOCKS + reduce_blocks, 256, 0, stream>>>(
        feat, out_idx, out_w, out_proj, copies, out_map, nc);
}